// Round 12
// baseline (512.398 us; speedup 1.0000x reference)
//
#include <hip/hip_runtime.h>
#include <hip/hip_bf16.h>

typedef _Float16 half8_t __attribute__((ext_vector_type(8)));
typedef _Float16 half4_t __attribute__((ext_vector_type(4)));
typedef _Float16 half2_t __attribute__((ext_vector_type(2)));
typedef float float4_t __attribute__((ext_vector_type(4)));

// ---------------- radix-partition CSR build ----------------
// bucket b = dst >> SH (NBK <= 512). Edge chunks of CHUNK per workgroup.
// M[b*WG + w] = #edges of chunk w landing in bucket b; after k_colscan it is
// the per-chunk exclusive offset within bucket b. All hot counters are LDS.

__global__ __launch_bounds__(256) void k_hist(const int* __restrict__ dst, int E, int SH,
                                              int NBK, int WG, int CH, int* __restrict__ M) {
    extern __shared__ int lh[];
    for (int i = threadIdx.x; i < NBK; i += 256) lh[i] = 0;
    __syncthreads();
    int wg = blockIdx.x;
    int e0 = wg * CH, e1 = min(E, e0 + CH);
    for (int e = e0 + threadIdx.x; e < e1; e += 256)
        atomicAdd(&lh[dst[e] >> SH], 1);
    __syncthreads();
    for (int i = threadIdx.x; i < NBK; i += 256) M[i * WG + wg] = lh[i];
}

__global__ __launch_bounds__(256) void k_colscan(int* __restrict__ M, int WG,
                                                 int* __restrict__ totals) {
    __shared__ int s[256];
    int b = blockIdx.x, t = threadIdx.x;
    int v = (t < WG) ? M[b * WG + t] : 0;
    s[t] = v;
    __syncthreads();
    for (int off = 1; off < 256; off <<= 1) {
        int u = (t >= off) ? s[t - off] : 0;
        __syncthreads();
        s[t] += u;
        __syncthreads();
    }
    if (t < WG) M[b * WG + t] = s[t] - v;   // exclusive within bucket
    if (t == 255) totals[b] = s[255];
}

__global__ __launch_bounds__(512) void k_bucketscan(const int* __restrict__ totals, int NBK,
                                                    int E, int* __restrict__ base) {
    __shared__ int s[512];
    int t = threadIdx.x;
    int v = (t < NBK) ? totals[t] : 0;
    s[t] = v;
    __syncthreads();
    for (int off = 1; off < 512; off <<= 1) {
        int u = (t >= off) ? s[t - off] : 0;
        __syncthreads();
        s[t] += u;
        __syncthreads();
    }
    if (t < NBK) base[t] = s[t] - v;
    if (t == 0) base[NBK] = E;
}

// pack: low 23 bits = src node, high 9 bits = dst - (b<<SH). Valid for N < 2^23, SH <= 9.
__global__ __launch_bounds__(256) void k_scatter(const int* __restrict__ src,
                                                 const int* __restrict__ dst, int E, int SH,
                                                 int NBK, int WG, int CH,
                                                 const int* __restrict__ M,
                                                 const int* __restrict__ base,
                                                 unsigned* __restrict__ ebuf) {
    extern __shared__ int cur[];
    int wg = blockIdx.x;
    for (int i = threadIdx.x; i < NBK; i += 256) cur[i] = base[i] + M[i * WG + wg];
    __syncthreads();
    int e0 = wg * CH, e1 = min(E, e0 + CH);
    for (int e = e0 + threadIdx.x; e < e1; e += 256) {
        int d = dst[e];
        int b = d >> SH;
        int pos = atomicAdd(&cur[b], 1);                 // LDS atomic, wg-private
        ebuf[pos] = (unsigned)src[e] | ((unsigned)(d - (b << SH)) << 23);
    }
}

// one wg per bucket: LDS degree histogram -> local pair-scan -> rp/dinv, then
// second ebuf pass writes colx (bucket-local window, LDS cursors).
__global__ __launch_bounds__(256) void k_cntfill(const unsigned* __restrict__ ebuf,
                                                 const int* __restrict__ base, int SH, int N,
                                                 int E, float* __restrict__ dinv,
                                                 int* __restrict__ rp, int* __restrict__ colx) {
    __shared__ int h[512];
    __shared__ int cur[512];
    __shared__ int s[256];
    int b = blockIdx.x, t = threadIdx.x;
    int n0 = b << SH;
    int nb = min(N - n0, 1 << SH);
    for (int i = t; i < nb; i += 256) h[i] = 0;
    __syncthreads();
    int e0 = base[b], e1 = base[b + 1];
    for (int e = e0 + t; e < e1; e += 256)
        atomicAdd(&h[ebuf[e] >> 23], 1);
    __syncthreads();
    int i0 = 2 * t, i1 = 2 * t + 1;
    int a0 = (i0 < nb) ? h[i0] : 0;
    int a1 = (i1 < nb) ? h[i1] : 0;
    int ps = a0 + a1;
    s[t] = ps;
    __syncthreads();
    for (int off = 1; off < 256; off <<= 1) {
        int u = (t >= off) ? s[t - off] : 0;
        __syncthreads();
        s[t] += u;
        __syncthreads();
    }
    int excl = s[t] - ps;
    if (i0 < nb) {
        int r0 = e0 + excl;
        cur[i0] = r0;
        rp[n0 + i0] = r0;
        dinv[n0 + i0] = rsqrtf((float)(a0 + 1));
    }
    if (i1 < nb) {
        int r1 = e0 + excl + a0;
        cur[i1] = r1;
        rp[n0 + i1] = r1;
        dinv[n0 + i1] = rsqrtf((float)(a1 + 1));
    }
    if (b == (int)gridDim.x - 1 && t == 0) rp[N] = E;
    __syncthreads();
    for (int e = e0 + t; e < e1; e += 256) {
        unsigned v = ebuf[e];
        int pos = atomicAdd(&cur[v >> 23], 1);           // LDS atomic, wg-private
        colx[pos] = (int)(v & 0x7FFFFFu);
    }
}

// gptr[g] = first index i where batch[i] >= g (batch is sorted); gptr[G] = N.
__global__ void k_gptr(const int* __restrict__ batch, int N, int G, int* __restrict__ gptr) {
    int g = blockIdx.x * blockDim.x + threadIdx.x;
    if (g > G) return;
    int lo = 0, hi = N;
    while (lo < hi) {
        int mid = (lo + hi) >> 1;
        if (batch[mid] < g) lo = mid + 1; else hi = mid;
    }
    gptr[g] = lo;
}

// ---------------- W prep: Wt[n][k] = (fp16) W[k][n], for both layers ----------------

__global__ __launch_bounds__(256) void k_wprep(const float* __restrict__ W0,
                                               const float* __restrict__ W1,
                                               _Float16* __restrict__ Wt0,
                                               _Float16* __restrict__ Wt1) {
    int idx = blockIdx.x * 256 + threadIdx.x;   // 16384 elements, grid 64
    int n = idx >> 7, k = idx & 127;
    Wt0[n * 128 + k] = (_Float16)W0[k * 128 + n];
    Wt1[n * 128 + k] = (_Float16)W1[k * 128 + n];
}

// ---------------- MFMA GEMM: out[row] = (act(X[row]) @ W) * dinv[row] (fp16 out) ----------------
// 4 waves/block, 16 rows/wave. A-frags direct from global; B = half8 from
// L1/L2-resident Wt[n][k]. C/D: col=lane&15, row=quad*4+reg.

__global__ __launch_bounds__(256) void k_gemmM(const float* __restrict__ X,
                                               const _Float16* __restrict__ Wt,
                                               const float* __restrict__ dinv,
                                               _Float16* __restrict__ out, int N) {
    int t = threadIdx.x;
    int wv = t >> 6, lane = t & 63;
    int m = lane & 15, quad = lane >> 4;
    int rowbase = blockIdx.x * 64 + wv * 16;
    int arow = rowbase + m;
    int arowc = (arow < N) ? arow : (N - 1);
    const float* xr = X + (size_t)arowc * 128;

    float4_t acc[8];
    #pragma unroll
    for (int i = 0; i < 8; i++) acc[i] = (float4_t){0.f, 0.f, 0.f, 0.f};

    #pragma unroll
    for (int kc = 0; kc < 4; kc++) {
        int k0 = kc * 32 + quad * 8;
        float4 xa = *(const float4*)(xr + k0);
        float4 xb = *(const float4*)(xr + k0 + 4);
        float xv[8] = {xa.x, xa.y, xa.z, xa.w, xb.x, xb.y, xb.z, xb.w};
        half8_t a;
        #pragma unroll
        for (int j = 0; j < 8; j++) a[j] = (_Float16)xv[j];
        #pragma unroll
        for (int nt = 0; nt < 8; nt++) {
            half8_t b = *(const half8_t*)(Wt + (size_t)(nt * 16 + m) * 128 + k0);
            acc[nt] = __builtin_amdgcn_mfma_f32_16x16x32_f16(a, b, acc[nt], 0, 0, 0);
        }
    }

    float dv[4];
    #pragma unroll
    for (int r = 0; r < 4; r++) {
        int row = rowbase + quad * 4 + r;
        dv[r] = dinv[(row < N) ? row : (N - 1)];
    }
    #pragma unroll
    for (int r = 0; r < 4; r++) {
        int row = rowbase + quad * 4 + r;
        if (row < N) {
            _Float16* o = out + (size_t)row * 128 + m;
            #pragma unroll
            for (int nt = 0; nt < 8; nt++)
                o[nt * 16] = (_Float16)(acc[nt][r] * dv[r]);
        }
    }
}

// fp16-input variant with BN+ReLU fused into A-frag loads (layer 2)
__global__ __launch_bounds__(256) void k_gemmM16(const _Float16* __restrict__ X,
                                                 const _Float16* __restrict__ Wt,
                                                 const float* __restrict__ scale,
                                                 const float* __restrict__ shift,
                                                 const float* __restrict__ dinv,
                                                 _Float16* __restrict__ out, int N) {
    int t = threadIdx.x;
    int wv = t >> 6, lane = t & 63;
    int m = lane & 15, quad = lane >> 4;
    int rowbase = blockIdx.x * 64 + wv * 16;
    int arow = rowbase + m;
    int arowc = (arow < N) ? arow : (N - 1);
    const _Float16* xr = X + (size_t)arowc * 128;

    float4_t acc[8];
    #pragma unroll
    for (int i = 0; i < 8; i++) acc[i] = (float4_t){0.f, 0.f, 0.f, 0.f};

    #pragma unroll
    for (int kc = 0; kc < 4; kc++) {
        int k0 = kc * 32 + quad * 8;
        half8_t x8 = *(const half8_t*)(xr + k0);
        float4 sa = *(const float4*)(scale + k0);
        float4 sb = *(const float4*)(scale + k0 + 4);
        float4 ha = *(const float4*)(shift + k0);
        float4 hb = *(const float4*)(shift + k0 + 4);
        float sv[8] = {sa.x, sa.y, sa.z, sa.w, sb.x, sb.y, sb.z, sb.w};
        float hv[8] = {ha.x, ha.y, ha.z, ha.w, hb.x, hb.y, hb.z, hb.w};
        half8_t a;
        #pragma unroll
        for (int j = 0; j < 8; j++)
            a[j] = (_Float16)fmaxf(fmaf((float)x8[j], sv[j], hv[j]), 0.f);
        #pragma unroll
        for (int nt = 0; nt < 8; nt++) {
            half8_t b = *(const half8_t*)(Wt + (size_t)(nt * 16 + m) * 128 + k0);
            acc[nt] = __builtin_amdgcn_mfma_f32_16x16x32_f16(a, b, acc[nt], 0, 0, 0);
        }
    }

    float dv[4];
    #pragma unroll
    for (int r = 0; r < 4; r++) {
        int row = rowbase + quad * 4 + r;
        dv[r] = dinv[(row < N) ? row : (N - 1)];
    }
    #pragma unroll
    for (int r = 0; r < 4; r++) {
        int row = rowbase + quad * 4 + r;
        if (row < N) {
            _Float16* o = out + (size_t)row * 128 + m;
            #pragma unroll
            for (int nt = 0; nt < 8; nt++)
                o[nt * 16] = (_Float16)(acc[nt][r] * dv[r]);
        }
    }
}

// ---------------- Aggregation: out[i] = dinv[i]*(hs[i] + sum_{j in in(i)} hs[j]) + b ----------------
// One wave per node; half-waves process alternating edges; fp16 output.

__global__ __launch_bounds__(256) void k_agg(const _Float16* __restrict__ hs,
                                             const int* __restrict__ rp,
                                             const int* __restrict__ colx,
                                             const float* __restrict__ dinv,
                                             const float* __restrict__ bias,
                                             _Float16* __restrict__ out, int N) {
    int wave = (blockIdx.x * 256 + threadIdx.x) >> 6;
    int lane = threadIdx.x & 63;
    if (wave >= N) return;
    int i = wave;
    int half = lane >> 5;
    int cq = lane & 31;                 // col quad: cols 4*cq .. 4*cq+3
    const half4_t* row4 = (const half4_t*)hs;   // 32 half4 per row

    float4 s0 = make_float4(0.f, 0.f, 0.f, 0.f);
    float4 s1 = make_float4(0.f, 0.f, 0.f, 0.f);
    float4 s2 = make_float4(0.f, 0.f, 0.f, 0.f);
    float4 s3 = make_float4(0.f, 0.f, 0.f, 0.f);

    int k0 = rp[i], k1 = rp[i + 1];
    int k = k0 + half;
    for (; k + 6 < k1; k += 8) {
        int j0 = colx[k];
        int j1 = colx[k + 2];
        int j2 = colx[k + 4];
        int j3 = colx[k + 6];
        half4_t v0 = row4[(size_t)j0 * 32 + cq];
        half4_t v1 = row4[(size_t)j1 * 32 + cq];
        half4_t v2 = row4[(size_t)j2 * 32 + cq];
        half4_t v3 = row4[(size_t)j3 * 32 + cq];
        s0.x += (float)v0.x; s0.y += (float)v0.y; s0.z += (float)v0.z; s0.w += (float)v0.w;
        s1.x += (float)v1.x; s1.y += (float)v1.y; s1.z += (float)v1.z; s1.w += (float)v1.w;
        s2.x += (float)v2.x; s2.y += (float)v2.y; s2.z += (float)v2.z; s2.w += (float)v2.w;
        s3.x += (float)v3.x; s3.y += (float)v3.y; s3.z += (float)v3.z; s3.w += (float)v3.w;
    }
    for (; k < k1; k += 2) {
        int j = colx[k];
        half4_t v = row4[(size_t)j * 32 + cq];
        s0.x += (float)v.x; s0.y += (float)v.y; s0.z += (float)v.z; s0.w += (float)v.w;
    }
    float4 a;
    a.x = (s0.x + s1.x) + (s2.x + s3.x);
    a.y = (s0.y + s1.y) + (s2.y + s3.y);
    a.z = (s0.z + s1.z) + (s2.z + s3.z);
    a.w = (s0.w + s1.w) + (s2.w + s3.w);
    a.x += __shfl_xor(a.x, 32);
    a.y += __shfl_xor(a.y, 32);
    a.z += __shfl_xor(a.z, 32);
    a.w += __shfl_xor(a.w, 32);
    half4_t sv = row4[(size_t)i * 32 + cq];
    a.x += (float)sv.x; a.y += (float)sv.y; a.z += (float)sv.z; a.w += (float)sv.w;

    float d = dinv[i];
    float4 b4 = ((const float4*)bias)[cq];
    if (half == 0) {
        half4_t o;
        o.x = (_Float16)fmaf(a.x, d, b4.x);
        o.y = (_Float16)fmaf(a.y, d, b4.y);
        o.z = (_Float16)fmaf(a.z, d, b4.z);
        o.w = (_Float16)fmaf(a.w, d, b4.w);
        ((half4_t*)out)[(size_t)i * 32 + cq] = o;
    }
}

// ---------------- BN stats (fp16 input): per-block partials, NO global atomics ----------------
// part[blk][0..127] = partial sum, part[blk][128..255] = partial sumsq.

__global__ __launch_bounds__(256) void k_stats(const _Float16* __restrict__ x, int N,
                                               float* __restrict__ part) {
    int lane = threadIdx.x & 63;
    int wv = threadIdx.x >> 6;
    int gw = blockIdx.x * 4 + wv;
    int stride = gridDim.x * 4;
    const half2_t* b = (const half2_t*)x;
    float2 s = make_float2(0.f, 0.f), q = make_float2(0.f, 0.f);
    for (int i = gw; i < N; i += stride) {
        half2_t v = b[(size_t)i * 64 + lane];
        float vx = (float)v.x, vy = (float)v.y;
        s.x += vx; s.y += vy;
        q.x += vx * vx; q.y += vy * vy;
    }
    __shared__ float ls[4][128];
    __shared__ float lq[4][128];
    ls[wv][2 * lane] = s.x; ls[wv][2 * lane + 1] = s.y;
    lq[wv][2 * lane] = q.x; lq[wv][2 * lane + 1] = q.y;
    __syncthreads();
    int t = threadIdx.x;
    if (t < 128) {
        float* o = part + (size_t)blockIdx.x * 256;
        o[t] = ls[0][t] + ls[1][t] + ls[2][t] + ls[3][t];
        o[128 + t] = lq[0][t] + lq[1][t] + lq[2][t] + lq[3][t];
    }
}

// single block: reduce part[NB][256] -> scale/shift
__global__ __launch_bounds__(256) void k_bnp2(const float* __restrict__ part, int NB,
                                              const float* __restrict__ g,
                                              const float* __restrict__ be, int N,
                                              float* __restrict__ scale,
                                              float* __restrict__ shift) {
    __shared__ float red[256];
    int t = threadIdx.x;
    float acc = 0.f;
    for (int i = 0; i < NB; i += 4) {
        acc += part[(size_t)i * 256 + t] + part[(size_t)(i + 1) * 256 + t] +
               part[(size_t)(i + 2) * 256 + t] + part[(size_t)(i + 3) * 256 + t];
    }
    red[t] = acc;
    __syncthreads();
    if (t < 128) {
        float invN = 1.0f / (float)N;
        float mu = red[t] * invN;
        float var = fmaxf(red[128 + t] * invN - mu * mu, 0.f);
        float s = g[t] * rsqrtf(var + 1e-5f);
        scale[t] = s;
        shift[t] = fmaf(-mu, s, be[t]);
    }
}

// ---------------- Pooling: node-parallel, per-wave run flush (fp16 input) ----------------

__global__ __launch_bounds__(256) void k_pool2(const _Float16* __restrict__ x,
                                               const int* __restrict__ batch,
                                               const float* __restrict__ scale,
                                               const float* __restrict__ shift,
                                               float* __restrict__ psum, int N) {
    int nw = gridDim.x * 4;
    int w = blockIdx.x * 4 + (threadIdx.x >> 6);
    int lane = threadIdx.x & 63;
    int per = (N + nw - 1) / nw;
    int i0 = w * per, i1 = min(N, i0 + per);
    if (i0 >= i1) return;
    const half2_t* b = (const half2_t*)x;
    float2 s2 = ((const float2*)scale)[lane];
    float2 h2 = ((const float2*)shift)[lane];
    float2 acc = make_float2(0.f, 0.f);
    int g = batch[i0];
    for (int i = i0; i < i1; i++) {
        int gi = batch[i];
        if (gi != g) {   // wave-uniform branch
            atomicAdd(&psum[g * 128 + 2 * lane], acc.x);
            atomicAdd(&psum[g * 128 + 2 * lane + 1], acc.y);
            acc = make_float2(0.f, 0.f);
            g = gi;
        }
        half2_t v = b[(size_t)i * 64 + lane];
        acc.x += fmaxf(fmaf((float)v.x, s2.x, h2.x), 0.f);
        acc.y += fmaxf(fmaf((float)v.y, s2.y, h2.y), 0.f);
    }
    atomicAdd(&psum[g * 128 + 2 * lane], acc.x);
    atomicAdd(&psum[g * 128 + 2 * lane + 1], acc.y);
}

// ---------------- Head: out[g][o] = (psum[g]/cnt[g]) @ Wout[:,o] + bout[o] ----------------

__global__ __launch_bounds__(64) void k_final(const float* __restrict__ psum,
                                              const int* __restrict__ gptr,
                                              const float* __restrict__ Wout,
                                              const float* __restrict__ bout,
                                              float* __restrict__ out, int O) {
    int g = blockIdx.x, o = threadIdx.x;
    int cnt = gptr[g + 1] - gptr[g];
    float inv = 1.0f / fmaxf((float)cnt, 1.f);
    float acc = 0.f;
    for (int c = 0; c < 128; c++) acc = fmaf(psum[g * 128 + c], Wout[c * O + o], acc);
    out[g * O + o] = fmaf(acc, inv, bout[o]);
}

// ---------------- Host launch ----------------

extern "C" void kernel_launch(void* const* d_in, const int* in_sizes, int n_in,
                              void* d_out, int out_size, void* d_ws, size_t ws_size,
                              hipStream_t stream) {
    const float* x    = (const float*)d_in[0];
    const int*   edge = (const int*)d_in[1];
    const int*   batch= (const int*)d_in[2];
    const float* W0   = (const float*)d_in[4];
    const float* b0   = (const float*)d_in[5];
    const float* g0   = (const float*)d_in[6];
    const float* be0  = (const float*)d_in[7];
    const float* W1   = (const float*)d_in[8];
    const float* b1   = (const float*)d_in[9];
    const float* g1   = (const float*)d_in[10];
    const float* be1  = (const float*)d_in[11];
    const float* Wout = (const float*)d_in[12];
    const float* bout = (const float*)d_in[13];
    float* out = (float*)d_out;

    const int Hh  = in_sizes[5];              // 128
    const int Fin = in_sizes[4] / Hh;         // 128
    const int N   = in_sizes[0] / Fin;        // 100000
    const int E   = in_sizes[1] / 2;          // 1600000
    const int O   = in_sizes[13];             // 64
    const int G   = out_size / O;             // 128
    (void)Hh; (void)n_in; (void)ws_size;

    // bucket shift: smallest SH >= 8 with <= 512 buckets (pack needs SH <= 9, N < 2^23)
    int SH = 8;
    while (((N + (1 << SH) - 1) >> SH) > 512) SH++;
    const int NBK = (N + (1 << SH) - 1) >> SH;
    const int CH  = ((E + 255) / 256 > 8192) ? (E + 255) / 256 : 8192;  // chunk, keep WG<=256
    const int WG  = (E + CH - 1) / CH;
    const int SB  = 512;   // stats blocks

    char* p = (char*)d_ws;
    auto alloc = [&](size_t bytes) -> void* {
        void* r = (void*)p;
        p += (bytes + 255) & ~(size_t)255;
        return r;
    };
    _Float16* A   = (_Float16*)alloc((size_t)N * 128 * 2);   // fp16 gather table
    _Float16* B   = (_Float16*)alloc((size_t)N * 128 * 2);   // fp16 layer output
    float* dinv   = (float*)alloc((size_t)N * 4);
    int*   rp     = (int*)alloc((size_t)(N + 1) * 4);
    int*   colx   = (int*)alloc((size_t)E * 4);
    unsigned* ebuf= (unsigned*)alloc((size_t)E * 4);
    int*   M      = (int*)alloc((size_t)NBK * WG * 4);
    int*   totals = (int*)alloc((size_t)NBK * 4);
    int*   base   = (int*)alloc((size_t)(NBK + 1) * 4);
    float* part   = (float*)alloc((size_t)SB * 256 * 4);     // stats partials
    float* bn     = (float*)alloc(512 * 4);   // [scale1|shift1|scale2|shift2]
    int*   gptr   = (int*)alloc((size_t)(G + 1) * 4);
    float* psum   = (float*)alloc((size_t)G * 128 * 4);
    _Float16* Wt0 = (_Float16*)alloc(128 * 128 * 2);
    _Float16* Wt1 = (_Float16*)alloc(128 * 128 * 2);

    hipMemsetAsync(psum, 0, (size_t)G * 128 * 4, stream);

    const int* src = edge;
    const int* dst = edge + E;

    // radix-partition CSR build (no global atomics, no global scans)
    k_hist<<<WG, 256, NBK * 4, stream>>>(dst, E, SH, NBK, WG, CH, M);
    k_colscan<<<NBK, 256, 0, stream>>>(M, WG, totals);
    k_bucketscan<<<1, 512, 0, stream>>>(totals, NBK, E, base);
    k_scatter<<<WG, 256, NBK * 4, stream>>>(src, dst, E, SH, NBK, WG, CH, M, base, ebuf);
    k_cntfill<<<NBK, 256, 0, stream>>>(ebuf, base, SH, N, E, dinv, rp, colx);
    k_gptr<<<(G + 64) / 64, 64, 0, stream>>>(batch, N, G, gptr);
    k_wprep<<<64, 256, 0, stream>>>(W0, W1, Wt0, Wt1);

    // Layer 1 (MFMA GEMM fp32 in)
    k_gemmM<<<(N + 63) / 64, 256, 0, stream>>>(x, Wt0, dinv, A, N);
    k_agg<<<(N + 3) / 4, 256, 0, stream>>>(A, rp, colx, dinv, b0, B, N);
    k_stats<<<SB, 256, 0, stream>>>(B, N, part);
    k_bnp2<<<1, 256, 0, stream>>>(part, SB, g0, be0, N, bn, bn + 128);

    // Layer 2 (fp16 in, BN+ReLU fused into MFMA A-frag loads)
    k_gemmM16<<<(N + 63) / 64, 256, 0, stream>>>(B, Wt1, bn, bn + 128, dinv, A, N);
    k_agg<<<(N + 3) / 4, 256, 0, stream>>>(A, rp, colx, dinv, b1, B, N);
    k_stats<<<SB, 256, 0, stream>>>(B, N, part);
    k_bnp2<<<1, 256, 0, stream>>>(part, SB, g1, be1, N, bn + 256, bn + 384);

    // Pool (BN+ReLU fused) + head (mean division fused)
    k_pool2<<<512, 256, 0, stream>>>(B, batch, bn + 256, bn + 384, psum, N);
    k_final<<<G, 64, 0, stream>>>(psum, gptr, Wout, bout, out, O);
}

// Round 13
// 450.824 us; speedup vs baseline: 1.1366x; 1.1366x over previous
//
#include <hip/hip_runtime.h>
#include <hip/hip_bf16.h>

typedef _Float16 half8_t __attribute__((ext_vector_type(8)));
typedef _Float16 half4_t __attribute__((ext_vector_type(4)));
typedef _Float16 half2_t __attribute__((ext_vector_type(2)));
typedef float float4_t __attribute__((ext_vector_type(4)));

// ---------------- radix-partition CSR build ----------------
// bucket b = dst >> SH (NBK <= 512). Edge chunks of CHUNK per workgroup.
// M[b*WG + w] = #edges of chunk w landing in bucket b; after k_colscan it is
// the per-chunk exclusive offset within bucket b. All hot counters are LDS.

__global__ __launch_bounds__(256) void k_hist(const int* __restrict__ dst, int E, int SH,
                                              int NBK, int WG, int CH, int* __restrict__ M) {
    extern __shared__ int lh[];
    for (int i = threadIdx.x; i < NBK; i += 256) lh[i] = 0;
    __syncthreads();
    int wg = blockIdx.x;
    int e0 = wg * CH, e1 = min(E, e0 + CH);
    for (int e = e0 + threadIdx.x; e < e1; e += 256)
        atomicAdd(&lh[dst[e] >> SH], 1);
    __syncthreads();
    for (int i = threadIdx.x; i < NBK; i += 256) M[i * WG + wg] = lh[i];
}

__global__ __launch_bounds__(256) void k_colscan(int* __restrict__ M, int WG,
                                                 int* __restrict__ totals) {
    __shared__ int s[256];
    int b = blockIdx.x, t = threadIdx.x;
    int v = (t < WG) ? M[b * WG + t] : 0;
    s[t] = v;
    __syncthreads();
    for (int off = 1; off < 256; off <<= 1) {
        int u = (t >= off) ? s[t - off] : 0;
        __syncthreads();
        s[t] += u;
        __syncthreads();
    }
    if (t < WG) M[b * WG + t] = s[t] - v;   // exclusive within bucket
    if (t == 255) totals[b] = s[255];
}

__global__ __launch_bounds__(512) void k_bucketscan(const int* __restrict__ totals, int NBK,
                                                    int E, int* __restrict__ base) {
    __shared__ int s[512];
    int t = threadIdx.x;
    int v = (t < NBK) ? totals[t] : 0;
    s[t] = v;
    __syncthreads();
    for (int off = 1; off < 512; off <<= 1) {
        int u = (t >= off) ? s[t - off] : 0;
        __syncthreads();
        s[t] += u;
        __syncthreads();
    }
    if (t < NBK) base[t] = s[t] - v;
    if (t == 0) base[NBK] = E;
}

// pack: low 23 bits = src node, high 9 bits = dst - (b<<SH). Valid for N < 2^23, SH <= 9.
__global__ __launch_bounds__(256) void k_scatter(const int* __restrict__ src,
                                                 const int* __restrict__ dst, int E, int SH,
                                                 int NBK, int WG, int CH,
                                                 const int* __restrict__ M,
                                                 const int* __restrict__ base,
                                                 unsigned* __restrict__ ebuf) {
    extern __shared__ int cur[];
    int wg = blockIdx.x;
    for (int i = threadIdx.x; i < NBK; i += 256) cur[i] = base[i] + M[i * WG + wg];
    __syncthreads();
    int e0 = wg * CH, e1 = min(E, e0 + CH);
    for (int e = e0 + threadIdx.x; e < e1; e += 256) {
        int d = dst[e];
        int b = d >> SH;
        int pos = atomicAdd(&cur[b], 1);                 // LDS atomic, wg-private
        ebuf[pos] = (unsigned)src[e] | ((unsigned)(d - (b << SH)) << 23);
    }
}

// one wg per bucket: LDS degree histogram -> local pair-scan -> rp/dinv, then
// second ebuf pass writes colx (bucket-local window, LDS cursors).
// Idle-capacity side jobs (consumed only by later dispatches):
//   blocks 0..63:  Wt transpose slices;  block 64: gptr binary search;
//   blocks 65..96: psum zero;            block 97: sums zero.
__global__ __launch_bounds__(256) void k_cntfill(const unsigned* __restrict__ ebuf,
                                                 const int* __restrict__ base, int SH, int N,
                                                 int E, float* __restrict__ dinv,
                                                 int* __restrict__ rp, int* __restrict__ colx,
                                                 const float* __restrict__ W0,
                                                 const float* __restrict__ W1,
                                                 _Float16* __restrict__ Wt0,
                                                 _Float16* __restrict__ Wt1,
                                                 const int* __restrict__ batch, int G,
                                                 int* __restrict__ gptr,
                                                 float* __restrict__ psum,
                                                 float* __restrict__ sums) {
    __shared__ int h[512];
    __shared__ int cur[512];
    __shared__ int s[256];
    int b = blockIdx.x, t = threadIdx.x;

    // side jobs
    if (b < 64) {
        int idx = b * 256 + t;            // 16384 elements over 64 blocks
        int n = idx >> 7, k = idx & 127;
        Wt0[n * 128 + k] = (_Float16)W0[k * 128 + n];
        Wt1[n * 128 + k] = (_Float16)W1[k * 128 + n];
    } else if (b == 64) {
        if (t <= G) {
            int g = t;
            int lo = 0, hi = N;
            while (lo < hi) {
                int mid = (lo + hi) >> 1;
                if (batch[mid] < g) lo = mid + 1; else hi = mid;
            }
            gptr[g] = lo;
        }
    } else if (b < 97) {
        int i0 = (b - 65) * 512 + t;      // G*128 = 16384 floats over 32 blocks
        psum[i0] = 0.f;
        psum[i0 + 256] = 0.f;
    } else if (b == 97) {
        if (t < 256) { sums[t] = 0.f; sums[t + 256] = 0.f; }
    }

    // main cntfill work
    int n0 = b << SH;
    int nb = min(N - n0, 1 << SH);
    for (int i = t; i < nb; i += 256) h[i] = 0;
    __syncthreads();
    int e0 = base[b], e1 = base[b + 1];
    for (int e = e0 + t; e < e1; e += 256)
        atomicAdd(&h[ebuf[e] >> 23], 1);
    __syncthreads();
    int i0 = 2 * t, i1 = 2 * t + 1;
    int a0 = (i0 < nb) ? h[i0] : 0;
    int a1 = (i1 < nb) ? h[i1] : 0;
    int ps = a0 + a1;
    s[t] = ps;
    __syncthreads();
    for (int off = 1; off < 256; off <<= 1) {
        int u = (t >= off) ? s[t - off] : 0;
        __syncthreads();
        s[t] += u;
        __syncthreads();
    }
    int excl = s[t] - ps;
    if (i0 < nb) {
        int r0 = e0 + excl;
        cur[i0] = r0;
        rp[n0 + i0] = r0;
        dinv[n0 + i0] = rsqrtf((float)(a0 + 1));
    }
    if (i1 < nb) {
        int r1 = e0 + excl + a0;
        cur[i1] = r1;
        rp[n0 + i1] = r1;
        dinv[n0 + i1] = rsqrtf((float)(a1 + 1));
    }
    if (b == (int)gridDim.x - 1 && t == 0) rp[N] = E;
    __syncthreads();
    for (int e = e0 + t; e < e1; e += 256) {
        unsigned v = ebuf[e];
        int pos = atomicAdd(&cur[v >> 23], 1);           // LDS atomic, wg-private
        colx[pos] = (int)(v & 0x7FFFFFu);
    }
}

// ---------------- MFMA GEMM: out[row] = (act(X[row]) @ W) * dinv[row] (fp16 out) ----------------
// 4 waves/block, 16 rows/wave. A-frags direct from global; B = half8 from
// L1/L2-resident Wt[n][k]. C/D: col=lane&15, row=quad*4+reg.

__global__ __launch_bounds__(256) void k_gemmM(const float* __restrict__ X,
                                               const _Float16* __restrict__ Wt,
                                               const float* __restrict__ dinv,
                                               _Float16* __restrict__ out, int N) {
    int t = threadIdx.x;
    int wv = t >> 6, lane = t & 63;
    int m = lane & 15, quad = lane >> 4;
    int rowbase = blockIdx.x * 64 + wv * 16;
    int arow = rowbase + m;
    int arowc = (arow < N) ? arow : (N - 1);
    const float* xr = X + (size_t)arowc * 128;

    float4_t acc[8];
    #pragma unroll
    for (int i = 0; i < 8; i++) acc[i] = (float4_t){0.f, 0.f, 0.f, 0.f};

    #pragma unroll
    for (int kc = 0; kc < 4; kc++) {
        int k0 = kc * 32 + quad * 8;
        float4 xa = *(const float4*)(xr + k0);
        float4 xb = *(const float4*)(xr + k0 + 4);
        float xv[8] = {xa.x, xa.y, xa.z, xa.w, xb.x, xb.y, xb.z, xb.w};
        half8_t a;
        #pragma unroll
        for (int j = 0; j < 8; j++) a[j] = (_Float16)xv[j];
        #pragma unroll
        for (int nt = 0; nt < 8; nt++) {
            half8_t b = *(const half8_t*)(Wt + (size_t)(nt * 16 + m) * 128 + k0);
            acc[nt] = __builtin_amdgcn_mfma_f32_16x16x32_f16(a, b, acc[nt], 0, 0, 0);
        }
    }

    float dv[4];
    #pragma unroll
    for (int r = 0; r < 4; r++) {
        int row = rowbase + quad * 4 + r;
        dv[r] = dinv[(row < N) ? row : (N - 1)];
    }
    #pragma unroll
    for (int r = 0; r < 4; r++) {
        int row = rowbase + quad * 4 + r;
        if (row < N) {
            _Float16* o = out + (size_t)row * 128 + m;
            #pragma unroll
            for (int nt = 0; nt < 8; nt++)
                o[nt * 16] = (_Float16)(acc[nt][r] * dv[r]);
        }
    }
}

// fp16-input variant with BN+ReLU fused into A-frag loads (layer 2)
__global__ __launch_bounds__(256) void k_gemmM16(const _Float16* __restrict__ X,
                                                 const _Float16* __restrict__ Wt,
                                                 const float* __restrict__ scale,
                                                 const float* __restrict__ shift,
                                                 const float* __restrict__ dinv,
                                                 _Float16* __restrict__ out, int N) {
    int t = threadIdx.x;
    int wv = t >> 6, lane = t & 63;
    int m = lane & 15, quad = lane >> 4;
    int rowbase = blockIdx.x * 64 + wv * 16;
    int arow = rowbase + m;
    int arowc = (arow < N) ? arow : (N - 1);
    const _Float16* xr = X + (size_t)arowc * 128;

    float4_t acc[8];
    #pragma unroll
    for (int i = 0; i < 8; i++) acc[i] = (float4_t){0.f, 0.f, 0.f, 0.f};

    #pragma unroll
    for (int kc = 0; kc < 4; kc++) {
        int k0 = kc * 32 + quad * 8;
        half8_t x8 = *(const half8_t*)(xr + k0);
        float4 sa = *(const float4*)(scale + k0);
        float4 sb = *(const float4*)(scale + k0 + 4);
        float4 ha = *(const float4*)(shift + k0);
        float4 hb = *(const float4*)(shift + k0 + 4);
        float sv[8] = {sa.x, sa.y, sa.z, sa.w, sb.x, sb.y, sb.z, sb.w};
        float hv[8] = {ha.x, ha.y, ha.z, ha.w, hb.x, hb.y, hb.z, hb.w};
        half8_t a;
        #pragma unroll
        for (int j = 0; j < 8; j++)
            a[j] = (_Float16)fmaxf(fmaf((float)x8[j], sv[j], hv[j]), 0.f);
        #pragma unroll
        for (int nt = 0; nt < 8; nt++) {
            half8_t b = *(const half8_t*)(Wt + (size_t)(nt * 16 + m) * 128 + k0);
            acc[nt] = __builtin_amdgcn_mfma_f32_16x16x32_f16(a, b, acc[nt], 0, 0, 0);
        }
    }

    float dv[4];
    #pragma unroll
    for (int r = 0; r < 4; r++) {
        int row = rowbase + quad * 4 + r;
        dv[r] = dinv[(row < N) ? row : (N - 1)];
    }
    #pragma unroll
    for (int r = 0; r < 4; r++) {
        int row = rowbase + quad * 4 + r;
        if (row < N) {
            _Float16* o = out + (size_t)row * 128 + m;
            #pragma unroll
            for (int nt = 0; nt < 8; nt++)
                o[nt * 16] = (_Float16)(acc[nt][r] * dv[r]);
        }
    }
}

// ---------------- Aggregation: out[i] = dinv[i]*(hs[i] + sum_{j in in(i)} hs[j]) + b ----------------
// One wave per node; half-waves process alternating edges; fp16 output.

__global__ __launch_bounds__(256) void k_agg(const _Float16* __restrict__ hs,
                                             const int* __restrict__ rp,
                                             const int* __restrict__ colx,
                                             const float* __restrict__ dinv,
                                             const float* __restrict__ bias,
                                             _Float16* __restrict__ out, int N) {
    int wave = (blockIdx.x * 256 + threadIdx.x) >> 6;
    int lane = threadIdx.x & 63;
    if (wave >= N) return;
    int i = wave;
    int half = lane >> 5;
    int cq = lane & 31;                 // col quad: cols 4*cq .. 4*cq+3
    const half4_t* row4 = (const half4_t*)hs;   // 32 half4 per row

    float4 s0 = make_float4(0.f, 0.f, 0.f, 0.f);
    float4 s1 = make_float4(0.f, 0.f, 0.f, 0.f);
    float4 s2 = make_float4(0.f, 0.f, 0.f, 0.f);
    float4 s3 = make_float4(0.f, 0.f, 0.f, 0.f);

    int k0 = rp[i], k1 = rp[i + 1];
    int k = k0 + half;
    for (; k + 6 < k1; k += 8) {
        int j0 = colx[k];
        int j1 = colx[k + 2];
        int j2 = colx[k + 4];
        int j3 = colx[k + 6];
        half4_t v0 = row4[(size_t)j0 * 32 + cq];
        half4_t v1 = row4[(size_t)j1 * 32 + cq];
        half4_t v2 = row4[(size_t)j2 * 32 + cq];
        half4_t v3 = row4[(size_t)j3 * 32 + cq];
        s0.x += (float)v0.x; s0.y += (float)v0.y; s0.z += (float)v0.z; s0.w += (float)v0.w;
        s1.x += (float)v1.x; s1.y += (float)v1.y; s1.z += (float)v1.z; s1.w += (float)v1.w;
        s2.x += (float)v2.x; s2.y += (float)v2.y; s2.z += (float)v2.z; s2.w += (float)v2.w;
        s3.x += (float)v3.x; s3.y += (float)v3.y; s3.z += (float)v3.z; s3.w += (float)v3.w;
    }
    for (; k < k1; k += 2) {
        int j = colx[k];
        half4_t v = row4[(size_t)j * 32 + cq];
        s0.x += (float)v.x; s0.y += (float)v.y; s0.z += (float)v.z; s0.w += (float)v.w;
    }
    float4 a;
    a.x = (s0.x + s1.x) + (s2.x + s3.x);
    a.y = (s0.y + s1.y) + (s2.y + s3.y);
    a.z = (s0.z + s1.z) + (s2.z + s3.z);
    a.w = (s0.w + s1.w) + (s2.w + s3.w);
    a.x += __shfl_xor(a.x, 32);
    a.y += __shfl_xor(a.y, 32);
    a.z += __shfl_xor(a.z, 32);
    a.w += __shfl_xor(a.w, 32);
    half4_t sv = row4[(size_t)i * 32 + cq];
    a.x += (float)sv.x; a.y += (float)sv.y; a.z += (float)sv.z; a.w += (float)sv.w;

    float d = dinv[i];
    float4 b4 = ((const float4*)bias)[cq];
    if (half == 0) {
        half4_t o;
        o.x = (_Float16)fmaf(a.x, d, b4.x);
        o.y = (_Float16)fmaf(a.y, d, b4.y);
        o.z = (_Float16)fmaf(a.z, d, b4.z);
        o.w = (_Float16)fmaf(a.w, d, b4.w);
        ((half4_t*)out)[(size_t)i * 32 + cq] = o;
    }
}

// ---------------- BN stats (fp16 input) ----------------

__global__ __launch_bounds__(256) void k_stats(const _Float16* __restrict__ x, int N,
                                               float* __restrict__ sums) {
    int lane = threadIdx.x & 63;
    int wv = threadIdx.x >> 6;
    int gw = blockIdx.x * 4 + wv;
    int stride = gridDim.x * 4;
    const half2_t* b = (const half2_t*)x;
    float2 s = make_float2(0.f, 0.f), q = make_float2(0.f, 0.f);
    for (int i = gw; i < N; i += stride) {
        half2_t v = b[(size_t)i * 64 + lane];
        float vx = (float)v.x, vy = (float)v.y;
        s.x += vx; s.y += vy;
        q.x += vx * vx; q.y += vy * vy;
    }
    __shared__ float ls[4][128];
    __shared__ float lq[4][128];
    ls[wv][2 * lane] = s.x; ls[wv][2 * lane + 1] = s.y;
    lq[wv][2 * lane] = q.x; lq[wv][2 * lane + 1] = q.y;
    __syncthreads();
    int t = threadIdx.x;
    if (t < 128) {
        float ts = ls[0][t] + ls[1][t] + ls[2][t] + ls[3][t];
        float tq = lq[0][t] + lq[1][t] + lq[2][t] + lq[3][t];
        atomicAdd(&sums[t], ts);
        atomicAdd(&sums[128 + t], tq);
    }
}

__global__ void k_bnp(const float* __restrict__ sums, const float* __restrict__ g,
                      const float* __restrict__ be, int N, float* __restrict__ scale,
                      float* __restrict__ shift) {
    int c = threadIdx.x;
    if (c < 128) {
        float invN = 1.0f / (float)N;
        float mu = sums[c] * invN;
        float var = sums[128 + c] * invN - mu * mu;
        var = fmaxf(var, 0.f);
        float s = g[c] * rsqrtf(var + 1e-5f);
        scale[c] = s;
        shift[c] = fmaf(-mu, s, be[c]);
    }
}

// ---------------- Pooling: node-parallel, per-wave run flush (fp16 input) ----------------

__global__ __launch_bounds__(256) void k_pool2(const _Float16* __restrict__ x,
                                               const int* __restrict__ batch,
                                               const float* __restrict__ scale,
                                               const float* __restrict__ shift,
                                               float* __restrict__ psum, int N) {
    int nw = gridDim.x * 4;
    int w = blockIdx.x * 4 + (threadIdx.x >> 6);
    int lane = threadIdx.x & 63;
    int per = (N + nw - 1) / nw;
    int i0 = w * per, i1 = min(N, i0 + per);
    if (i0 >= i1) return;
    const half2_t* b = (const half2_t*)x;
    float2 s2 = ((const float2*)scale)[lane];
    float2 h2 = ((const float2*)shift)[lane];
    float2 acc = make_float2(0.f, 0.f);
    int g = batch[i0];
    for (int i = i0; i < i1; i++) {
        int gi = batch[i];
        if (gi != g) {   // wave-uniform branch
            atomicAdd(&psum[g * 128 + 2 * lane], acc.x);
            atomicAdd(&psum[g * 128 + 2 * lane + 1], acc.y);
            acc = make_float2(0.f, 0.f);
            g = gi;
        }
        half2_t v = b[(size_t)i * 64 + lane];
        acc.x += fmaxf(fmaf((float)v.x, s2.x, h2.x), 0.f);
        acc.y += fmaxf(fmaf((float)v.y, s2.y, h2.y), 0.f);
    }
    atomicAdd(&psum[g * 128 + 2 * lane], acc.x);
    atomicAdd(&psum[g * 128 + 2 * lane + 1], acc.y);
}

// ---------------- Head: out[g][o] = (psum[g]/cnt[g]) @ Wout[:,o] + bout[o] ----------------

__global__ __launch_bounds__(64) void k_final(const float* __restrict__ psum,
                                              const int* __restrict__ gptr,
                                              const float* __restrict__ Wout,
                                              const float* __restrict__ bout,
                                              float* __restrict__ out, int O) {
    int g = blockIdx.x, o = threadIdx.x;
    int cnt = gptr[g + 1] - gptr[g];
    float inv = 1.0f / fmaxf((float)cnt, 1.f);
    float acc = 0.f;
    for (int c = 0; c < 128; c++) acc = fmaf(psum[g * 128 + c], Wout[c * O + o], acc);
    out[g * O + o] = fmaf(acc, inv, bout[o]);
}

// ---------------- Host launch ----------------

extern "C" void kernel_launch(void* const* d_in, const int* in_sizes, int n_in,
                              void* d_out, int out_size, void* d_ws, size_t ws_size,
                              hipStream_t stream) {
    const float* x    = (const float*)d_in[0];
    const int*   edge = (const int*)d_in[1];
    const int*   batch= (const int*)d_in[2];
    const float* W0   = (const float*)d_in[4];
    const float* b0   = (const float*)d_in[5];
    const float* g0   = (const float*)d_in[6];
    const float* be0  = (const float*)d_in[7];
    const float* W1   = (const float*)d_in[8];
    const float* b1   = (const float*)d_in[9];
    const float* g1   = (const float*)d_in[10];
    const float* be1  = (const float*)d_in[11];
    const float* Wout = (const float*)d_in[12];
    const float* bout = (const float*)d_in[13];
    float* out = (float*)d_out;

    const int Hh  = in_sizes[5];              // 128
    const int Fin = in_sizes[4] / Hh;         // 128
    const int N   = in_sizes[0] / Fin;        // 100000
    const int E   = in_sizes[1] / 2;          // 1600000
    const int O   = in_sizes[13];             // 64
    const int G   = out_size / O;             // 128
    (void)Hh; (void)n_in; (void)ws_size;

    // bucket shift: smallest SH >= 8 with <= 512 buckets (pack needs SH <= 9, N < 2^23)
    int SH = 8;
    while (((N + (1 << SH) - 1) >> SH) > 512) SH++;
    const int NBK = (N + (1 << SH) - 1) >> SH;
    const int CH  = ((E + 255) / 256 > 8192) ? (E + 255) / 256 : 8192;  // chunk, keep WG<=256
    const int WG  = (E + CH - 1) / CH;

    char* p = (char*)d_ws;
    auto alloc = [&](size_t bytes) -> void* {
        void* r = (void*)p;
        p += (bytes + 255) & ~(size_t)255;
        return r;
    };
    _Float16* A   = (_Float16*)alloc((size_t)N * 128 * 2);   // fp16 gather table
    _Float16* B   = (_Float16*)alloc((size_t)N * 128 * 2);   // fp16 layer output
    float* dinv   = (float*)alloc((size_t)N * 4);
    int*   rp     = (int*)alloc((size_t)(N + 1) * 4);
    int*   colx   = (int*)alloc((size_t)E * 4);
    unsigned* ebuf= (unsigned*)alloc((size_t)E * 4);
    int*   M      = (int*)alloc((size_t)NBK * WG * 4);
    int*   totals = (int*)alloc((size_t)NBK * 4);
    int*   base   = (int*)alloc((size_t)(NBK + 1) * 4);
    float* sums   = (float*)alloc(512 * 4);   // [sum1|sq1|sum2|sq2]
    float* bn     = (float*)alloc(512 * 4);   // [scale1|shift1|scale2|shift2]
    int*   gptr   = (int*)alloc((size_t)(G + 1) * 4);
    float* psum   = (float*)alloc((size_t)G * 128 * 4);
    _Float16* Wt0 = (_Float16*)alloc(128 * 128 * 2);
    _Float16* Wt1 = (_Float16*)alloc(128 * 128 * 2);

    const int* src = edge;
    const int* dst = edge + E;

    // radix-partition CSR build; k_cntfill also does wprep/gptr/psum-zero/sums-zero
    k_hist<<<WG, 256, NBK * 4, stream>>>(dst, E, SH, NBK, WG, CH, M);
    k_colscan<<<NBK, 256, 0, stream>>>(M, WG, totals);
    k_bucketscan<<<1, 512, 0, stream>>>(totals, NBK, E, base);
    k_scatter<<<WG, 256, NBK * 4, stream>>>(src, dst, E, SH, NBK, WG, CH, M, base, ebuf);
    k_cntfill<<<NBK, 256, 0, stream>>>(ebuf, base, SH, N, E, dinv, rp, colx,
                                       W0, W1, Wt0, Wt1, batch, G, gptr, psum, sums);

    // Layer 1 (MFMA GEMM fp32 in)
    k_gemmM<<<(N + 63) / 64, 256, 0, stream>>>(x, Wt0, dinv, A, N);
    k_agg<<<(N + 3) / 4, 256, 0, stream>>>(A, rp, colx, dinv, b0, B, N);
    k_stats<<<512, 256, 0, stream>>>(B, N, sums);
    k_bnp<<<1, 128, 0, stream>>>(sums, g0, be0, N, bn, bn + 128);

    // Layer 2 (fp16 in, BN+ReLU fused into MFMA A-frag loads)
    k_gemmM16<<<(N + 63) / 64, 256, 0, stream>>>(B, Wt1, bn, bn + 128, dinv, A, N);
    k_agg<<<(N + 3) / 4, 256, 0, stream>>>(A, rp, colx, dinv, b1, B, N);
    k_stats<<<512, 256, 0, stream>>>(B, N, sums + 256);
    k_bnp<<<1, 128, 0, stream>>>(sums + 256, g1, be1, N, bn + 256, bn + 384);

    // Pool (BN+ReLU fused) + head (mean division fused)
    k_pool2<<<512, 256, 0, stream>>>(B, batch, bn + 256, bn + 384, psum, N);
    k_final<<<G, 64, 0, stream>>>(psum, gptr, Wout, bout, out, O);
}